// Round 1
// baseline (1007.757 us; speedup 1.0000x reference)
//
#include <hip/hip_runtime.h>
#include <hip/hip_bf16.h>
#include <stdint.h>

// Problem constants
#define D_MODEL 1024
#define HEADS   16
#define DK      64
#define BATCH   128
#define NTOK    256
#define MROWS   (BATCH * NTOK)   // 32768

typedef __attribute__((ext_vector_type(8))) short bf16x8;
typedef __attribute__((ext_vector_type(4))) float f32x4;

// fp32 -> bf16 round-to-nearest-even
__device__ __forceinline__ unsigned short f2b_rne(float f) {
    union { float f; unsigned int u; } c; c.f = f;
    unsigned int u = c.u;
    unsigned int r = (u + 0x7FFFu + ((u >> 16) & 1u)) >> 16;
    return (unsigned short)r;
}

// async global->LDS, 16B per lane, dest = wave-uniform base + lane*16
__device__ __forceinline__ void async16(const void* g, void* l) {
    __builtin_amdgcn_global_load_lds(
        (__attribute__((address_space(1))) void*)g,
        (__attribute__((address_space(3))) void*)l,
        16, 0, 0);
}

// ---------------- fp32 -> bf16 convert (vectorized) ----------------
__global__ __launch_bounds__(256)
void f2b_kernel(const float* __restrict__ x, ushort* __restrict__ y, int n4) {
    int i = blockIdx.x * blockDim.x + threadIdx.x;
    int stride = gridDim.x * blockDim.x;
    for (; i < n4; i += stride) {
        float4 v = ((const float4*)x)[i];
        ushort4 o;
        o.x = f2b_rne(v.x); o.y = f2b_rne(v.y);
        o.z = f2b_rne(v.z); o.w = f2b_rne(v.w);
        ((ushort4*)y)[i] = o;
    }
}

// ---------------- bf16 NT GEMM: C[m,e] = sum_k A[m,k] * B[e,k] ----------------
// A: M x K row-major bf16, B: N x K row-major bf16 (i.e. weight (e,d))
// MODE 0: out bf16, permuted scatter: dst[((e>>6)*256 + (m&255))*128 + (m>>8)]*64 + (e&63)
//         value = (acc + bias[e]) * alpha
// MODE 1: out fp32 row-major [m*N + e], value = acc + bias[e]
template<int MODE>
__global__ __launch_bounds__(256)
void gemm_nt(const ushort* __restrict__ A, const ushort* __restrict__ B,
             const float* __restrict__ bias, void* __restrict__ Cout,
             int M, int N, int K, float alpha)
{
    __shared__ ushort As[128 * 32];
    __shared__ ushort Bs[128 * 32];

    const int tid  = threadIdx.x;
    const int wave = tid >> 6, lane = tid & 63;
    const int quad = lane >> 4, l15 = lane & 15;
    const int pm = blockIdx.x * 128, pn = blockIdx.y * 128;
    const int wm = (wave & 1) * 64, wn = (wave >> 1) * 64;

    f32x4 acc[4][4] = {};

    // staging: group g = wave*2+i covers rows g*16 + (lane>>2), cols (lane&3)*8 .. +8
    const int rg = lane >> 2;
    const int c8 = (lane & 3) * 8;
    const ushort* Abase0 = A + (size_t)(pm + wave * 32 + rg) * K + c8;
    const ushort* Abase1 = Abase0 + (size_t)16 * K;
    const ushort* Bbase0 = B + (size_t)(pn + wave * 32 + rg) * K + c8;
    const ushort* Bbase1 = Bbase0 + (size_t)16 * K;

    for (int k0 = 0; k0 < K; k0 += 32) {
        __syncthreads();  // previous tile fully consumed
        async16(Abase0 + k0, &As[wave * 1024]);
        async16(Abase1 + k0, &As[wave * 1024 + 512]);
        async16(Bbase0 + k0, &Bs[wave * 1024]);
        async16(Bbase1 + k0, &Bs[wave * 1024 + 512]);
        __syncthreads();  // vmcnt(0) drained by barrier semantics

        bf16x8 af[4], bfr[4];
        #pragma unroll
        for (int t = 0; t < 4; t++) {
            af[t]  = *(const bf16x8*)&As[(wm + t * 16 + l15) * 32 + quad * 8];
            bfr[t] = *(const bf16x8*)&Bs[(wn + t * 16 + l15) * 32 + quad * 8];
        }
        #pragma unroll
        for (int i = 0; i < 4; i++)
            #pragma unroll
            for (int j = 0; j < 4; j++)
                acc[i][j] = __builtin_amdgcn_mfma_f32_16x16x32_bf16(af[i], bfr[j], acc[i][j], 0, 0, 0);
    }

    if (MODE == 0) {
        ushort* out = (ushort*)Cout;
        #pragma unroll
        for (int i = 0; i < 4; i++) {
            const int mbase = pm + wm + i * 16 + quad * 4;
            #pragma unroll
            for (int j = 0; j < 4; j++) {
                const int e = pn + wn + j * 16 + l15;
                const float bv = bias[e];
                const int h = e >> 6, d = e & 63;
                #pragma unroll
                for (int r = 0; r < 4; r++) {
                    const int mm = mbase + r;
                    const int bb = mm >> 8, nn = mm & 255;
                    float val = (acc[i][j][r] + bv) * alpha;
                    out[(size_t)(((h << 8) + nn) * 128 + bb) * 64 + d] = f2b_rne(val);
                }
            }
        }
    } else {
        float* out = (float*)Cout;
        #pragma unroll
        for (int i = 0; i < 4; i++) {
            const int mbase = pm + wm + i * 16 + quad * 4;
            #pragma unroll
            for (int j = 0; j < 4; j++) {
                const int e = pn + wn + j * 16 + l15;
                const float bv = bias[e];
                #pragma unroll
                for (int r = 0; r < 4; r++) {
                    const int mm = mbase + r;
                    out[(size_t)mm * N + e] = acc[i][j][r] + bv;
                }
            }
        }
    }
}

// ---------------- intersample attention: one block per (h, n) ----------------
// Qp/Kp/Vp layout: [h][n][b][d] bf16 (scale already folded into Q)
// Output: Ob[(b*256 + n)*1024 + h*64 + d] bf16  (merged-head layout for final GEMM)
__global__ __launch_bounds__(256)
void attn_kernel(const ushort* __restrict__ Qp, const ushort* __restrict__ Kp,
                 const ushort* __restrict__ Vp, ushort* __restrict__ Ob)
{
    __shared__ ushort sm[24576];  // 48KB: sQ[0,8192) sK[8192,16384) sVt[16384,24576); P overlays [0,16384)

    const int tid  = threadIdx.x;
    const int wave = tid >> 6, lane = tid & 63;
    const int quad = lane >> 4, l15 = lane & 15;
    const int hn = blockIdx.x;
    const int h = hn >> 8, n = hn & 255;
    const size_t base = (size_t)hn * (BATCH * DK);

    // load Q, K tiles (contiguous 16KB each) and V transposed (Vt[d][c])
    {
        const uint4* Qg = (const uint4*)(Qp + base);
        const uint4* Kg = (const uint4*)(Kp + base);
        uint4* s4 = (uint4*)sm;
        #pragma unroll
        for (int i = 0; i < 4; i++) {
            int id = tid + i * 256;           // 0..1023 chunks of 8 bf16
            s4[id]        = Qg[id];
            s4[1024 + id] = Kg[id];
        }
        const uint4* Vg = (const uint4*)(Vp + base);
        #pragma unroll
        for (int i = 0; i < 4; i++) {
            int id = tid + i * 256;
            int c = id >> 3, d8 = (id & 7) * 8;
            uint4 vv = Vg[id];
            const ushort* vs = (const ushort*)&vv;
            #pragma unroll
            for (int j = 0; j < 8; j++)
                sm[16384 + (d8 + j) * 128 + c] = vs[j];
        }
    }
    __syncthreads();

    // S = Q K^T : wave handles rows [wave*32, wave*32+32), all 128 cols
    f32x4 accs[2][8] = {};
    #pragma unroll
    for (int kk = 0; kk < 64; kk += 32) {
        bf16x8 aq[2], bk8[8];
        #pragma unroll
        for (int mt = 0; mt < 2; mt++)
            aq[mt] = *(const bf16x8*)&sm[(wave * 32 + mt * 16 + l15) * 64 + kk + quad * 8];
        #pragma unroll
        for (int nt = 0; nt < 8; nt++)
            bk8[nt] = *(const bf16x8*)&sm[8192 + (nt * 16 + l15) * 64 + kk + quad * 8];
        #pragma unroll
        for (int mt = 0; mt < 2; mt++)
            #pragma unroll
            for (int nt = 0; nt < 8; nt++)
                accs[mt][nt] = __builtin_amdgcn_mfma_f32_16x16x32_bf16(aq[mt], bk8[nt], accs[mt][nt], 0, 0, 0);
    }

    // rowwise softmax in registers: row r held by the 16 lanes of this quad group
    #pragma unroll
    for (int mt = 0; mt < 2; mt++) {
        #pragma unroll
        for (int r = 0; r < 4; r++) {
            float mx = accs[mt][0][r];
            #pragma unroll
            for (int nt = 1; nt < 8; nt++) mx = fmaxf(mx, accs[mt][nt][r]);
            #pragma unroll
            for (int s = 1; s < 16; s <<= 1) mx = fmaxf(mx, __shfl_xor(mx, s, 64));
            float sum = 0.f;
            #pragma unroll
            for (int nt = 0; nt < 8; nt++) {
                float e = __expf(accs[mt][nt][r] - mx);
                accs[mt][nt][r] = e;
                sum += e;
            }
            #pragma unroll
            for (int s = 1; s < 16; s <<= 1) sum += __shfl_xor(sum, s, 64);
            float inv = 1.0f / sum;
            #pragma unroll
            for (int nt = 0; nt < 8; nt++) accs[mt][nt][r] *= inv;
        }
    }

    __syncthreads();  // all waves done reading sQ/sK before P overwrite

    // write P (bf16, C-layout -> row-major) into sm[0,16384)
    #pragma unroll
    for (int mt = 0; mt < 2; mt++)
        #pragma unroll
        for (int nt = 0; nt < 8; nt++)
            #pragma unroll
            for (int r = 0; r < 4; r++)
                sm[(wave * 32 + mt * 16 + quad * 4 + r) * 128 + nt * 16 + l15] =
                    f2b_rne(accs[mt][nt][r]);
    __syncthreads();

    // O = P V : P[b][c] at sm[0], Vt[d][c] at sm[16384]
    f32x4 acco[2][4] = {};
    #pragma unroll
    for (int kk = 0; kk < 128; kk += 32) {
        bf16x8 ap[2], bv8[4];
        #pragma unroll
        for (int mt = 0; mt < 2; mt++)
            ap[mt] = *(const bf16x8*)&sm[(wave * 32 + mt * 16 + l15) * 128 + kk + quad * 8];
        #pragma unroll
        for (int nt = 0; nt < 4; nt++)
            bv8[nt] = *(const bf16x8*)&sm[16384 + (nt * 16 + l15) * 128 + kk + quad * 8];
        #pragma unroll
        for (int mt = 0; mt < 2; mt++)
            #pragma unroll
            for (int nt = 0; nt < 4; nt++)
                acco[mt][nt] = __builtin_amdgcn_mfma_f32_16x16x32_bf16(ap[mt], bv8[nt], acco[mt][nt], 0, 0, 0);
    }

    #pragma unroll
    for (int mt = 0; mt < 2; mt++)
        #pragma unroll
        for (int nt = 0; nt < 4; nt++)
            #pragma unroll
            for (int r = 0; r < 4; r++) {
                int b = wave * 32 + mt * 16 + quad * 4 + r;
                int d = nt * 16 + l15;
                Ob[((size_t)b * NTOK + n) * D_MODEL + h * DK + d] = f2b_rne(acco[mt][nt][r]);
            }
}

extern "C" void kernel_launch(void* const* d_in, const int* in_sizes, int n_in,
                              void* d_out, int out_size, void* d_ws, size_t ws_size,
                              hipStream_t stream)
{
    const float* q  = (const float*)d_in[0];
    const float* k  = (const float*)d_in[1];
    const float* v  = (const float*)d_in[2];
    const float* Wq = (const float*)d_in[3];
    const float* bq = (const float*)d_in[4];
    const float* Wk = (const float*)d_in[5];
    const float* bk = (const float*)d_in[6];
    const float* Wv = (const float*)d_in[7];
    const float* bv = (const float*)d_in[8];
    const float* Wo = (const float*)d_in[9];
    const float* bo = (const float*)d_in[10];

    const int XE = MROWS * D_MODEL;       // 33,554,432 activation elements
    const int WE = D_MODEL * D_MODEL;     // 1,048,576 weight elements

    // workspace (bf16 as ushort): xb | Kp | Vp | Wb(x4)  = 200 MiB
    ushort* xb = (ushort*)d_ws;
    ushort* Kp = xb + (size_t)XE;
    ushort* Vp = Kp + (size_t)XE;
    ushort* Wb = Vp + (size_t)XE;
    // Qp (64 MiB) lives in d_out (128 MiB fp32) — consumed before the final GEMM writes it
    ushort* Qp = (ushort*)d_out;

    dim3 blk(256);
    dim3 ggemm(MROWS / 128, D_MODEL / 128);   // (256, 8)

    // convert weights to bf16 (once per call)
    f2b_kernel<<<dim3(512),  blk, 0, stream>>>(Wq, Wb + 0 * (size_t)WE, WE / 4);
    f2b_kernel<<<dim3(512),  blk, 0, stream>>>(Wk, Wb + 1 * (size_t)WE, WE / 4);
    f2b_kernel<<<dim3(512),  blk, 0, stream>>>(Wv, Wb + 2 * (size_t)WE, WE / 4);
    f2b_kernel<<<dim3(512),  blk, 0, stream>>>(Wo, Wb + 3 * (size_t)WE, WE / 4);

    // Q projection (scale 1/8 folded in), permuted to [h][n][b][d]
    f2b_kernel<<<dim3(4096), blk, 0, stream>>>(q, xb, XE / 4);
    gemm_nt<0><<<ggemm, blk, 0, stream>>>(xb, Wb + 0 * (size_t)WE, bq, Qp,
                                          MROWS, D_MODEL, D_MODEL, 0.125f);
    // K projection
    f2b_kernel<<<dim3(4096), blk, 0, stream>>>(k, xb, XE / 4);
    gemm_nt<0><<<ggemm, blk, 0, stream>>>(xb, Wb + 1 * (size_t)WE, bk, Kp,
                                          MROWS, D_MODEL, D_MODEL, 1.0f);
    // V projection
    f2b_kernel<<<dim3(4096), blk, 0, stream>>>(v, xb, XE / 4);
    gemm_nt<0><<<ggemm, blk, 0, stream>>>(xb, Wb + 2 * (size_t)WE, bv, Vp,
                                          MROWS, D_MODEL, D_MODEL, 1.0f);

    // intersample attention: one block per (h, n); writes merged-head bf16 into xb
    attn_kernel<<<dim3(HEADS * NTOK), blk, 0, stream>>>(Qp, Kp, Vp, xb);

    // output projection -> fp32 d_out
    gemm_nt<1><<<ggemm, blk, 0, stream>>>(xb, Wb + 3 * (size_t)WE, bo, d_out,
                                          MROWS, D_MODEL, D_MODEL, 1.0f);
}